// Round 1
// baseline (316.592 us; speedup 1.0000x reference)
//
#include <hip/hip_runtime.h>
#include <hip/hip_bf16.h>
#include <math.h>

#define NG   1024
#define IMGW 128
#define IMGH 128
#define NPIX (IMGW*IMGH)

// Workspace layout (floats):
//   [0, NG)          : tz (camera depth)
//   [NG, 11*NG)      : unsorted props, 10 arrays of NG: x2d,y2d,ca,cb,cc,r,g,b,op,valid
//   [11*NG, 21*NG)   : sorted props, same 10 arrays
#define PROP_X  0
#define PROP_Y  1
#define PROP_CA 2
#define PROP_CB 3
#define PROP_CC 4
#define PROP_R  5
#define PROP_G  6
#define PROP_B  7
#define PROP_OP 8
#define PROP_V  9

__global__ void preprocess_k(const float* __restrict__ means,
                             const float* __restrict__ scales,
                             const float* __restrict__ quats,
                             const float* __restrict__ opacities,
                             const float* __restrict__ sh0,
                             const float* __restrict__ shN,
                             const float* __restrict__ vm,   // 4x4 row-major
                             const float* __restrict__ Kc,   // 3x3 row-major
                             const int*   __restrict__ degp,
                             float* __restrict__ tz_out,
                             float* __restrict__ U) {
    int i = blockIdx.x * blockDim.x + threadIdx.x;
    if (i >= NG) return;

    // camera
    float R00=vm[0], R01=vm[1], R02=vm[2],  t0=vm[3];
    float R10=vm[4], R11=vm[5], R12=vm[6],  t1=vm[7];
    float R20=vm[8], R21=vm[9], R22=vm[10], t2=vm[11];
    float fx=Kc[0], cx=Kc[2], fy=Kc[4], cy=Kc[5];

    float mx=means[i*3+0], my=means[i*3+1], mz=means[i*3+2];
    float tx = R00*mx + R01*my + R02*mz + t0;
    float ty = R10*mx + R11*my + R12*mz + t1;
    float tz = R20*mx + R21*my + R22*mz + t2;

    float x2d = fx*tx/tz + cx;
    float y2d = fy*ty/tz + cy;

    // quat -> rotation
    float qw=quats[i*4+0], qx=quats[i*4+1], qy=quats[i*4+2], qz=quats[i*4+3];
    float qn = rsqrtf(qw*qw + qx*qx + qy*qy + qz*qz);
    qw*=qn; qx*=qn; qy*=qn; qz*=qn;
    float Rm[3][3];
    Rm[0][0]=1.f-2.f*(qy*qy+qz*qz); Rm[0][1]=2.f*(qx*qy-qw*qz); Rm[0][2]=2.f*(qx*qz+qw*qy);
    Rm[1][0]=2.f*(qx*qy+qw*qz); Rm[1][1]=1.f-2.f*(qx*qx+qz*qz); Rm[1][2]=2.f*(qy*qz-qw*qx);
    Rm[2][0]=2.f*(qx*qz-qw*qy); Rm[2][1]=2.f*(qy*qz+qw*qx); Rm[2][2]=1.f-2.f*(qx*qx+qy*qy);

    // M = R * diag(exp(scale)), cov3d = M M^T
    float s0=expf(scales[i*3+0]), s1=expf(scales[i*3+1]), s2=expf(scales[i*3+2]);
    float M[3][3];
    for (int r=0; r<3; ++r) { M[r][0]=Rm[r][0]*s0; M[r][1]=Rm[r][1]*s1; M[r][2]=Rm[r][2]*s2; }
    float C3[3][3];
    for (int r=0; r<3; ++r)
        for (int ccol=0; ccol<3; ++ccol)
            C3[r][ccol] = M[r][0]*M[ccol][0] + M[r][1]*M[ccol][1] + M[r][2]*M[ccol][2];

    // cov_cam = Rwc * cov3d * Rwc^T
    float Rw[3][3] = {{R00,R01,R02},{R10,R11,R12},{R20,R21,R22}};
    float A[3][3];
    for (int r=0; r<3; ++r)
        for (int k=0; k<3; ++k)
            A[r][k] = Rw[r][0]*C3[0][k] + Rw[r][1]*C3[1][k] + Rw[r][2]*C3[2][k];
    float CC[3][3];
    for (int r=0; r<3; ++r)
        for (int l=0; l<3; ++l)
            CC[r][l] = A[r][0]*Rw[l][0] + A[r][1]*Rw[l][1] + A[r][2]*Rw[l][2];

    // J (2x3) projection Jacobian
    float J00 = fx/tz, J02 = -fx*tx/(tz*tz);
    float J11 = fy/tz, J12 = -fy*ty/(tz*tz);
    // JC = J * cov_cam
    float JC00 = J00*CC[0][0] + J02*CC[2][0];
    float JC01 = J00*CC[0][1] + J02*CC[2][1];
    float JC02 = J00*CC[0][2] + J02*CC[2][2];
    float JC11 = J11*CC[1][1] + J12*CC[2][1];
    float JC12 = J11*CC[1][2] + J12*CC[2][2];
    // cov2d = JC * J^T
    float v00 = JC00*J00 + JC02*J02;
    float v01 = JC01*J11 + JC02*J12;
    float v11 = JC11*J11 + JC12*J12;

    float a = v00 + 0.3f;
    float b = v01;
    float c = v11 + 0.3f;
    float det = a*c - b*b;
    float ca =  c/det;
    float cb = -b/det;
    float cc =  a/det;

    bool valid = (tz > 0.01f) && (det > 1e-12f);

    // SH color
    float cpx = -(R00*t0 + R10*t1 + R20*t2);
    float cpy = -(R01*t0 + R11*t1 + R21*t2);
    float cpz = -(R02*t0 + R12*t1 + R22*t2);
    float dx = mx - cpx, dy = my - cpy, dz = mz - cpz;
    float dn = rsqrtf(dx*dx + dy*dy + dz*dz);
    float X = dx*dn, Y = dy*dn, Z = dz*dn;
    float xx = X*X, yy = Y*Y, zz = Z*Z;

    float basis[16];
    basis[0]  = 0.28209479177387814f;
    basis[1]  = -0.4886025119029199f * Y;
    basis[2]  =  0.4886025119029199f * Z;
    basis[3]  = -0.4886025119029199f * X;
    basis[4]  =  1.0925484305920792f * X*Y;
    basis[5]  = -1.0925484305920792f * Y*Z;
    basis[6]  =  0.31539156525252005f * (2.f*zz - xx - yy);
    basis[7]  = -1.0925484305920792f * X*Z;
    basis[8]  =  0.5462742152960396f * (xx - yy);
    basis[9]  = -0.5900435899266435f * Y * (3.f*xx - yy);
    basis[10] =  2.890611442640554f  * X*Y*Z;
    basis[11] = -0.4570457994644658f * Y * (4.f*zz - xx - yy);
    basis[12] =  0.3731763325901154f * Z * (2.f*zz - 3.f*xx - 3.f*yy);
    basis[13] = -0.4570457994644658f * X * (4.f*zz - xx - yy);
    basis[14] =  1.445305721320277f  * Z * (xx - yy);
    basis[15] = -0.5900435899266435f * X * (xx - yy);

    int deg = degp[0];
    int nsh = (deg + 1) * (deg + 1);
    if (nsh > 16) nsh = 16;

    float col[3];
    for (int ch = 0; ch < 3; ++ch) {
        float acc = 0.f;
        // k = 0 from sh0
        acc += basis[0] * sh0[i*3 + ch];
        for (int k = 1; k < nsh; ++k)
            acc += basis[k] * shN[(i*15 + (k-1))*3 + ch];
        acc += 0.5f;
        col[ch] = fmaxf(acc, 0.f);
    }

    float op = 1.f / (1.f + expf(-opacities[i]));

    tz_out[i] = tz;
    U[PROP_X *NG + i] = x2d;
    U[PROP_Y *NG + i] = y2d;
    U[PROP_CA*NG + i] = ca;
    U[PROP_CB*NG + i] = cb;
    U[PROP_CC*NG + i] = cc;
    U[PROP_R *NG + i] = col[0];
    U[PROP_G *NG + i] = col[1];
    U[PROP_B *NG + i] = col[2];
    U[PROP_OP*NG + i] = op;
    U[PROP_V *NG + i] = valid ? 1.f : 0.f;
}

// Stable argsort by tz via O(N^2) rank computation, then scatter to sorted arrays.
__global__ void sort_k(const float* __restrict__ tz,
                       const float* __restrict__ U,
                       float* __restrict__ S) {
    int i = blockIdx.x * blockDim.x + threadIdx.x;
    if (i >= NG) return;
    float ti = tz[i];
    int rank = 0;
    for (int j = 0; j < NG; ++j) {
        float tj = tz[j];
        rank += (tj < ti) || (tj == ti && j < i);
    }
    for (int k = 0; k < 10; ++k)
        S[k*NG + rank] = U[k*NG + i];
}

// One thread per pixel: front-to-back composite over all gaussians in depth order.
__global__ void render_k(const float* __restrict__ S,
                         const float* __restrict__ bg,
                         float* __restrict__ out) {
    int p = blockIdx.x * blockDim.x + threadIdx.x;
    if (p >= NPIX) return;
    float gx = (float)(p % IMGW) + 0.5f;
    float gy = (float)(p / IMGW) + 0.5f;

    const float* sx = S + PROP_X *NG;
    const float* sy = S + PROP_Y *NG;
    const float* sa = S + PROP_CA*NG;
    const float* sb = S + PROP_CB*NG;
    const float* sc = S + PROP_CC*NG;
    const float* sr = S + PROP_R *NG;
    const float* sg = S + PROP_G *NG;
    const float* sbl= S + PROP_B *NG;
    const float* so = S + PROP_OP*NG;
    const float* sv = S + PROP_V *NG;

    float T = 1.f;
    float r = 0.f, g = 0.f, b = 0.f;
    for (int n = 0; n < NG; ++n) {
        if (sv[n] == 0.f) continue;
        float dx = gx - sx[n];
        float dy = gy - sy[n];
        float sig = 0.5f * (sa[n]*dx*dx + sc[n]*dy*dy) + sb[n]*dx*dy;
        if (!(sig >= 0.f)) continue;
        float al = so[n] * __expf(-sig);
        if (al <= (1.f/255.f)) continue;
        al = fminf(al, 0.999f);
        float w = al * T;
        r += w * sr[n];
        g += w * sg[n];
        b += w * sbl[n];
        T *= (1.f - al);
    }
    out[p*3 + 0] = r + T * bg[0];
    out[p*3 + 1] = g + T * bg[1];
    out[p*3 + 2] = b + T * bg[2];
    out[NPIX*3 + p] = 1.f - T;
}

extern "C" void kernel_launch(void* const* d_in, const int* in_sizes, int n_in,
                              void* d_out, int out_size, void* d_ws, size_t ws_size,
                              hipStream_t stream) {
    const float* means     = (const float*)d_in[0];
    const float* scales    = (const float*)d_in[1];
    const float* quats     = (const float*)d_in[2];
    const float* opacities = (const float*)d_in[3];
    const float* sh0       = (const float*)d_in[4];
    const float* shN       = (const float*)d_in[5];
    const float* vm        = (const float*)d_in[6];
    const float* Kc        = (const float*)d_in[7];
    const float* bg        = (const float*)d_in[8];
    const int*   degp      = (const int*)  d_in[11];

    float* ws = (float*)d_ws;
    float* tz = ws;            // NG
    float* U  = ws + NG;       // 10*NG
    float* S  = ws + 11*NG;    // 10*NG

    float* out = (float*)d_out;

    preprocess_k<<<(NG + 255)/256, 256, 0, stream>>>(means, scales, quats, opacities,
                                                     sh0, shN, vm, Kc, degp, tz, U);
    sort_k<<<(NG + 255)/256, 256, 0, stream>>>(tz, U, S);
    render_k<<<(NPIX + 255)/256, 256, 0, stream>>>(S, bg, out);
}

// Round 2
// 144.194 us; speedup vs baseline: 2.1956x; 2.1956x over previous
//
#include <hip/hip_runtime.h>
#include <hip/hip_bf16.h>
#include <math.h>

#define NG   1024
#define IMGW 128
#define IMGH 128
#define NPIX (IMGW*IMGH)

// Workspace layout (floats):
//   tz : [0, NG)
//   UA : [NG, 5NG)    float4 (x2d, y2d, ca, cb)   unsorted
//   UB : [5NG, 9NG)   float4 (cc, r, g, b)        unsorted
//   UO : [9NG, 10NG)  float  (opacity, 0 if invalid)
//   SA : [10NG, 14NG) sorted
//   SB : [14NG, 18NG) sorted
//   SO : [18NG, 19NG) sorted

__global__ void preprocess_k(const float* __restrict__ means,
                             const float* __restrict__ scales,
                             const float* __restrict__ quats,
                             const float* __restrict__ opacities,
                             const float* __restrict__ sh0,
                             const float* __restrict__ shN,
                             const float* __restrict__ vm,   // 4x4 row-major
                             const float* __restrict__ Kc,   // 3x3 row-major
                             const int*   __restrict__ degp,
                             float* __restrict__ tz_out,
                             float4* __restrict__ UA,
                             float4* __restrict__ UB,
                             float*  __restrict__ UO) {
    int i = blockIdx.x * blockDim.x + threadIdx.x;
    if (i >= NG) return;

    float R00=vm[0], R01=vm[1], R02=vm[2],  t0=vm[3];
    float R10=vm[4], R11=vm[5], R12=vm[6],  t1=vm[7];
    float R20=vm[8], R21=vm[9], R22=vm[10], t2=vm[11];
    float fx=Kc[0], cx=Kc[2], fy=Kc[4], cy=Kc[5];

    float mx=means[i*3+0], my=means[i*3+1], mz=means[i*3+2];
    float tx = R00*mx + R01*my + R02*mz + t0;
    float ty = R10*mx + R11*my + R12*mz + t1;
    float tz = R20*mx + R21*my + R22*mz + t2;

    float x2d = fx*tx/tz + cx;
    float y2d = fy*ty/tz + cy;

    float qw=quats[i*4+0], qx=quats[i*4+1], qy=quats[i*4+2], qz=quats[i*4+3];
    float qn = rsqrtf(qw*qw + qx*qx + qy*qy + qz*qz);
    qw*=qn; qx*=qn; qy*=qn; qz*=qn;
    float Rm[3][3];
    Rm[0][0]=1.f-2.f*(qy*qy+qz*qz); Rm[0][1]=2.f*(qx*qy-qw*qz); Rm[0][2]=2.f*(qx*qz+qw*qy);
    Rm[1][0]=2.f*(qx*qy+qw*qz); Rm[1][1]=1.f-2.f*(qx*qx+qz*qz); Rm[1][2]=2.f*(qy*qz-qw*qx);
    Rm[2][0]=2.f*(qx*qz-qw*qy); Rm[2][1]=2.f*(qy*qz+qw*qx); Rm[2][2]=1.f-2.f*(qx*qx+qy*qy);

    float s0=expf(scales[i*3+0]), s1=expf(scales[i*3+1]), s2=expf(scales[i*3+2]);
    float M[3][3];
    for (int r=0; r<3; ++r) { M[r][0]=Rm[r][0]*s0; M[r][1]=Rm[r][1]*s1; M[r][2]=Rm[r][2]*s2; }
    float C3[3][3];
    for (int r=0; r<3; ++r)
        for (int ccol=0; ccol<3; ++ccol)
            C3[r][ccol] = M[r][0]*M[ccol][0] + M[r][1]*M[ccol][1] + M[r][2]*M[ccol][2];

    float Rw[3][3] = {{R00,R01,R02},{R10,R11,R12},{R20,R21,R22}};
    float A[3][3];
    for (int r=0; r<3; ++r)
        for (int k=0; k<3; ++k)
            A[r][k] = Rw[r][0]*C3[0][k] + Rw[r][1]*C3[1][k] + Rw[r][2]*C3[2][k];
    float CC[3][3];
    for (int r=0; r<3; ++r)
        for (int l=0; l<3; ++l)
            CC[r][l] = A[r][0]*Rw[l][0] + A[r][1]*Rw[l][1] + A[r][2]*Rw[l][2];

    float J00 = fx/tz, J02 = -fx*tx/(tz*tz);
    float J11 = fy/tz, J12 = -fy*ty/(tz*tz);
    float JC00 = J00*CC[0][0] + J02*CC[2][0];
    float JC01 = J00*CC[0][1] + J02*CC[2][1];
    float JC02 = J00*CC[0][2] + J02*CC[2][2];
    float JC11 = J11*CC[1][1] + J12*CC[2][1];
    float JC12 = J11*CC[1][2] + J12*CC[2][2];
    float v00 = JC00*J00 + JC02*J02;
    float v01 = JC01*J11 + JC02*J12;
    float v11 = JC11*J11 + JC12*J12;

    float a = v00 + 0.3f;
    float b = v01;
    float c = v11 + 0.3f;
    float det = a*c - b*b;
    float ca =  c/det;
    float cb = -b/det;
    float cc =  a/det;

    bool valid = (tz > 0.01f) && (det > 1e-12f);

    float cpx = -(R00*t0 + R10*t1 + R20*t2);
    float cpy = -(R01*t0 + R11*t1 + R21*t2);
    float cpz = -(R02*t0 + R12*t1 + R22*t2);
    float dx = mx - cpx, dy = my - cpy, dz = mz - cpz;
    float dn = rsqrtf(dx*dx + dy*dy + dz*dz);
    float X = dx*dn, Y = dy*dn, Z = dz*dn;
    float xx = X*X, yy = Y*Y, zz = Z*Z;

    float basis[16];
    basis[0]  = 0.28209479177387814f;
    basis[1]  = -0.4886025119029199f * Y;
    basis[2]  =  0.4886025119029199f * Z;
    basis[3]  = -0.4886025119029199f * X;
    basis[4]  =  1.0925484305920792f * X*Y;
    basis[5]  = -1.0925484305920792f * Y*Z;
    basis[6]  =  0.31539156525252005f * (2.f*zz - xx - yy);
    basis[7]  = -1.0925484305920792f * X*Z;
    basis[8]  =  0.5462742152960396f * (xx - yy);
    basis[9]  = -0.5900435899266435f * Y * (3.f*xx - yy);
    basis[10] =  2.890611442640554f  * X*Y*Z;
    basis[11] = -0.4570457994644658f * Y * (4.f*zz - xx - yy);
    basis[12] =  0.3731763325901154f * Z * (2.f*zz - 3.f*xx - 3.f*yy);
    basis[13] = -0.4570457994644658f * X * (4.f*zz - xx - yy);
    basis[14] =  1.445305721320277f  * Z * (xx - yy);
    basis[15] = -0.5900435899266435f * X * (xx - yy);

    int deg = degp[0];
    int nsh = (deg + 1) * (deg + 1);
    if (nsh > 16) nsh = 16;

    float col[3];
    for (int ch = 0; ch < 3; ++ch) {
        float acc = basis[0] * sh0[i*3 + ch];
        for (int k = 1; k < nsh; ++k)
            acc += basis[k] * shN[(i*15 + (k-1))*3 + ch];
        acc += 0.5f;
        col[ch] = fmaxf(acc, 0.f);
    }

    float op = 1.f / (1.f + expf(-opacities[i]));
    if (!valid) op = 0.f;   // alpha mask folds the valid flag (NaN-safe downstream)

    tz_out[i] = tz;
    UA[i] = make_float4(x2d, y2d, ca, cb);
    UB[i] = make_float4(cc, col[0], col[1], col[2]);
    UO[i] = op;
}

// Stable rank sort by tz. 16 blocks x 64 threads; tz staged in LDS (broadcast reads).
__global__ void sort_k(const float* __restrict__ tz,
                       const float4* __restrict__ UA,
                       const float4* __restrict__ UB,
                       const float*  __restrict__ UO,
                       float4* __restrict__ SA,
                       float4* __restrict__ SB,
                       float*  __restrict__ SO) {
    __shared__ float ltz[NG];
    int tid = threadIdx.x;
    for (int j = tid; j < NG; j += 64) ltz[j] = tz[j];
    __syncthreads();

    int i = blockIdx.x * 64 + tid;
    float ti = ltz[i];
    int rank = 0;
    #pragma unroll 8
    for (int j = 0; j < NG; ++j) {
        float tj = ltz[j];
        rank += (tj < ti) || (tj == ti && j < i);
    }
    SA[rank] = UA[i];
    SB[rank] = UB[i];
    SO[rank] = UO[i];
}

// One block per pixel. 256 threads, 4 gaussians/thread (contiguous, depth order).
// Parallel prefix-product of (1-alpha) gives each thread its exclusive transmittance.
__global__ void __launch_bounds__(256) render_k(
        const float4* __restrict__ SA,
        const float4* __restrict__ SB,
        const float*  __restrict__ SO,
        const float*  __restrict__ bg,
        float* __restrict__ out) {
    __shared__ float sc[256];
    __shared__ float4 red[256];

    int p = blockIdx.x;
    int t = threadIdx.x;
    float gx = (float)(p % IMGW) + 0.5f;
    float gy = (float)(p / IMGW) + 0.5f;

    int base = t * 4;
    float al[4], colr[4], colg[4], colb[4];
    #pragma unroll
    for (int k = 0; k < 4; ++k) {
        float4 A = SA[base + k];
        float4 B = SB[base + k];
        float  O = SO[base + k];
        float dx = gx - A.x;
        float dy = gy - A.y;
        float sig = 0.5f * (A.z*dx*dx + B.x*dy*dy) + A.w*dx*dy;
        float a = O * __expf(-sig);
        bool keep = (sig >= 0.f) && (a > (1.f/255.f));   // false for NaN sig/a
        al[k] = keep ? fminf(a, 0.999f) : 0.f;
        colr[k] = B.y; colg[k] = B.z; colb[k] = B.w;
    }

    // local (within-thread) prefix products and partial rgb
    float l = 1.f, pr = 0.f, pg = 0.f, pb = 0.f;
    #pragma unroll
    for (int k = 0; k < 4; ++k) {
        float w = al[k] * l;
        pr += w * colr[k];
        pg += w * colg[k];
        pb += w * colb[k];
        l *= (1.f - al[k]);
    }

    // block-wide inclusive product scan of per-thread total l
    sc[t] = l;
    __syncthreads();
    #pragma unroll
    for (int off = 1; off < 256; off <<= 1) {
        float v = (t >= off) ? sc[t - off] : 1.f;
        __syncthreads();
        sc[t] *= v;
        __syncthreads();
    }
    float E = (t == 0) ? 1.f : sc[t - 1];   // exclusive: transmittance before this thread
    float Tt = sc[255];                     // total transmittance

    // scale partials and block-reduce rgb
    red[t] = make_float4(pr * E, pg * E, pb * E, 0.f);
    __syncthreads();
    #pragma unroll
    for (int off = 128; off > 0; off >>= 1) {
        if (t < off) {
            red[t].x += red[t + off].x;
            red[t].y += red[t + off].y;
            red[t].z += red[t + off].z;
        }
        __syncthreads();
    }

    if (t == 0) {
        out[p*3 + 0] = red[0].x + Tt * bg[0];
        out[p*3 + 1] = red[0].y + Tt * bg[1];
        out[p*3 + 2] = red[0].z + Tt * bg[2];
        out[NPIX*3 + p] = 1.f - Tt;
    }
}

extern "C" void kernel_launch(void* const* d_in, const int* in_sizes, int n_in,
                              void* d_out, int out_size, void* d_ws, size_t ws_size,
                              hipStream_t stream) {
    const float* means     = (const float*)d_in[0];
    const float* scales    = (const float*)d_in[1];
    const float* quats     = (const float*)d_in[2];
    const float* opacities = (const float*)d_in[3];
    const float* sh0       = (const float*)d_in[4];
    const float* shN       = (const float*)d_in[5];
    const float* vm        = (const float*)d_in[6];
    const float* Kc        = (const float*)d_in[7];
    const float* bg        = (const float*)d_in[8];
    const int*   degp      = (const int*)  d_in[11];

    float* ws = (float*)d_ws;
    float*  tz = ws;                          // NG
    float4* UA = (float4*)(ws + NG);          // NG float4
    float4* UB = (float4*)(ws + 5*NG);        // NG float4
    float*  UO = ws + 9*NG;                   // NG
    float4* SA = (float4*)(ws + 10*NG);
    float4* SB = (float4*)(ws + 14*NG);
    float*  SO = ws + 18*NG;

    float* out = (float*)d_out;

    preprocess_k<<<(NG + 255)/256, 256, 0, stream>>>(means, scales, quats, opacities,
                                                     sh0, shN, vm, Kc, degp,
                                                     tz, UA, UB, UO);
    sort_k<<<16, 64, 0, stream>>>(tz, UA, UB, UO, SA, SB, SO);
    render_k<<<NPIX, 256, 0, stream>>>(SA, SB, SO, bg, out);
}

// Round 3
// 105.422 us; speedup vs baseline: 3.0031x; 1.3678x over previous
//
#include <hip/hip_runtime.h>
#include <hip/hip_bf16.h>
#include <math.h>

#define NG   1024
#define IMGW 128
#define IMGH 128
#define NPIX (IMGW*IMGH)
#define TILE 8
#define TILES_X (IMGW/TILE)   // 16
#define NTILES  (TILES_X*(IMGH/TILE))  // 256

// Packed per-gaussian properties (depth-sorted copies SA/SB/SC):
//   A: (x2d, y2d, ca, cb)
//   B: (cc, colR, colG, colB)
//   C: (op, rx, ry, 0)   rx/ry = conservative AABB half-extent of the
//                        alpha>1/255 ellipse; -1e30 sentinel if the gaussian
//                        can never pass the keep mask (invalid or op<=1/255).

__global__ void preprocess_k(const float* __restrict__ means,
                             const float* __restrict__ scales,
                             const float* __restrict__ quats,
                             const float* __restrict__ opacities,
                             const float* __restrict__ sh0,
                             const float* __restrict__ shN,
                             const float* __restrict__ vm,   // 4x4 row-major
                             const float* __restrict__ Kc,   // 3x3 row-major
                             const int*   __restrict__ degp,
                             float* __restrict__ tz_out,
                             float4* __restrict__ UA,
                             float4* __restrict__ UB,
                             float4* __restrict__ UC) {
    int i = blockIdx.x * blockDim.x + threadIdx.x;
    if (i >= NG) return;

    float R00=vm[0], R01=vm[1], R02=vm[2],  t0=vm[3];
    float R10=vm[4], R11=vm[5], R12=vm[6],  t1=vm[7];
    float R20=vm[8], R21=vm[9], R22=vm[10], t2=vm[11];
    float fx=Kc[0], cx=Kc[2], fy=Kc[4], cy=Kc[5];

    float mx=means[i*3+0], my=means[i*3+1], mz=means[i*3+2];
    float tx = R00*mx + R01*my + R02*mz + t0;
    float ty = R10*mx + R11*my + R12*mz + t1;
    float tz = R20*mx + R21*my + R22*mz + t2;

    float x2d = fx*tx/tz + cx;
    float y2d = fy*ty/tz + cy;

    float qw=quats[i*4+0], qx=quats[i*4+1], qy=quats[i*4+2], qz=quats[i*4+3];
    float qn = rsqrtf(qw*qw + qx*qx + qy*qy + qz*qz);
    qw*=qn; qx*=qn; qy*=qn; qz*=qn;
    float Rm[3][3];
    Rm[0][0]=1.f-2.f*(qy*qy+qz*qz); Rm[0][1]=2.f*(qx*qy-qw*qz); Rm[0][2]=2.f*(qx*qz+qw*qy);
    Rm[1][0]=2.f*(qx*qy+qw*qz); Rm[1][1]=1.f-2.f*(qx*qx+qz*qz); Rm[1][2]=2.f*(qy*qz-qw*qx);
    Rm[2][0]=2.f*(qx*qz-qw*qy); Rm[2][1]=2.f*(qy*qz+qw*qx); Rm[2][2]=1.f-2.f*(qx*qx+qy*qy);

    float s0=expf(scales[i*3+0]), s1=expf(scales[i*3+1]), s2=expf(scales[i*3+2]);
    float M[3][3];
    for (int r=0; r<3; ++r) { M[r][0]=Rm[r][0]*s0; M[r][1]=Rm[r][1]*s1; M[r][2]=Rm[r][2]*s2; }
    float C3[3][3];
    for (int r=0; r<3; ++r)
        for (int ccol=0; ccol<3; ++ccol)
            C3[r][ccol] = M[r][0]*M[ccol][0] + M[r][1]*M[ccol][1] + M[r][2]*M[ccol][2];

    float Rw[3][3] = {{R00,R01,R02},{R10,R11,R12},{R20,R21,R22}};
    float A[3][3];
    for (int r=0; r<3; ++r)
        for (int k=0; k<3; ++k)
            A[r][k] = Rw[r][0]*C3[0][k] + Rw[r][1]*C3[1][k] + Rw[r][2]*C3[2][k];
    float CC[3][3];
    for (int r=0; r<3; ++r)
        for (int l=0; l<3; ++l)
            CC[r][l] = A[r][0]*Rw[l][0] + A[r][1]*Rw[l][1] + A[r][2]*Rw[l][2];

    float J00 = fx/tz, J02 = -fx*tx/(tz*tz);
    float J11 = fy/tz, J12 = -fy*ty/(tz*tz);
    float JC00 = J00*CC[0][0] + J02*CC[2][0];
    float JC01 = J00*CC[0][1] + J02*CC[2][1];
    float JC02 = J00*CC[0][2] + J02*CC[2][2];
    float JC11 = J11*CC[1][1] + J12*CC[2][1];
    float JC12 = J11*CC[1][2] + J12*CC[2][2];
    float v00 = JC00*J00 + JC02*J02;
    float v01 = JC01*J11 + JC02*J12;
    float v11 = JC11*J11 + JC12*J12;

    float a = v00 + 0.3f;   // Sigma_00
    float b = v01;
    float c = v11 + 0.3f;   // Sigma_11
    float det = a*c - b*b;
    float ca =  c/det;
    float cb = -b/det;
    float cc =  a/det;

    bool valid = (tz > 0.01f) && (det > 1e-12f);

    float cpx = -(R00*t0 + R10*t1 + R20*t2);
    float cpy = -(R01*t0 + R11*t1 + R21*t2);
    float cpz = -(R02*t0 + R12*t1 + R22*t2);
    float dx = mx - cpx, dy = my - cpy, dz = mz - cpz;
    float dn = rsqrtf(dx*dx + dy*dy + dz*dz);
    float X = dx*dn, Y = dy*dn, Z = dz*dn;
    float xx = X*X, yy = Y*Y, zz = Z*Z;

    float basis[16];
    basis[0]  = 0.28209479177387814f;
    basis[1]  = -0.4886025119029199f * Y;
    basis[2]  =  0.4886025119029199f * Z;
    basis[3]  = -0.4886025119029199f * X;
    basis[4]  =  1.0925484305920792f * X*Y;
    basis[5]  = -1.0925484305920792f * Y*Z;
    basis[6]  =  0.31539156525252005f * (2.f*zz - xx - yy);
    basis[7]  = -1.0925484305920792f * X*Z;
    basis[8]  =  0.5462742152960396f * (xx - yy);
    basis[9]  = -0.5900435899266435f * Y * (3.f*xx - yy);
    basis[10] =  2.890611442640554f  * X*Y*Z;
    basis[11] = -0.4570457994644658f * Y * (4.f*zz - xx - yy);
    basis[12] =  0.3731763325901154f * Z * (2.f*zz - 3.f*xx - 3.f*yy);
    basis[13] = -0.4570457994644658f * X * (4.f*zz - xx - yy);
    basis[14] =  1.445305721320277f  * Z * (xx - yy);
    basis[15] = -0.5900435899266435f * X * (xx - yy);

    int deg = degp[0];
    int nsh = (deg + 1) * (deg + 1);
    if (nsh > 16) nsh = 16;

    float col[3];
    for (int ch = 0; ch < 3; ++ch) {
        float acc = basis[0] * sh0[i*3 + ch];
        for (int k = 1; k < nsh; ++k)
            acc += basis[k] * shN[(i*15 + (k-1))*3 + ch];
        acc += 0.5f;
        col[ch] = fmaxf(acc, 0.f);
    }

    float op = 1.f / (1.f + expf(-opacities[i]));

    // conservative bbox of the alpha>1/255 region: sigma <= s = ln(255*op)
    // ellipse d^T Sigma^{-1} d <= 2s  =>  |dx| <= sqrt(2s*Sigma00)
    float s = logf(255.f * op);
    float rx, ry;
    if (valid && s > 0.f) {
        rx = sqrtf(2.f * s * a) + 0.05f;   // +margin vs fp rounding
        ry = sqrtf(2.f * s * c) + 0.05f;
    } else {
        rx = -1e30f; ry = -1e30f;          // fails every overlap test (NaN-safe)
        op = 0.f;
    }

    tz_out[i] = tz;
    UA[i] = make_float4(x2d, y2d, ca, cb);
    UB[i] = make_float4(cc, col[0], col[1], col[2]);
    UC[i] = make_float4(op, rx, ry, 0.f);
}

// Stable rank sort: one block (1 wave) per gaussian; parallel count over j.
__global__ void __launch_bounds__(64) sort_k(
        const float* __restrict__ tz,
        const float4* __restrict__ UA,
        const float4* __restrict__ UB,
        const float4* __restrict__ UC,
        float4* __restrict__ SA,
        float4* __restrict__ SB,
        float4* __restrict__ SC) {
    int i = blockIdx.x;
    int lane = threadIdx.x;
    float ti = tz[i];
    int rank = 0;
    #pragma unroll
    for (int k = 0; k < NG/64; ++k) {
        int j = k*64 + lane;
        float tj = tz[j];
        rank += (tj < ti) || (tj == ti && j < i);
    }
    #pragma unroll
    for (int off = 32; off > 0; off >>= 1)
        rank += __shfl_down(rank, off, 64);
    if (lane == 0) {
        SA[rank] = UA[i];
        SB[rank] = UB[i];
        SC[rank] = UC[i];
    }
}

// One wave per 8x8 tile. Phase 1: order-preserving ballot-compaction of
// gaussians overlapping this tile into LDS. Phase 2: per-pixel front-to-back
// composite over the compacted list (broadcast LDS reads).
__global__ void __launch_bounds__(64) render_k(
        const float4* __restrict__ SA,
        const float4* __restrict__ SB,
        const float4* __restrict__ SC,
        const float*  __restrict__ bg,
        float* __restrict__ out) {
    __shared__ float4 lA[NG];
    __shared__ float4 lB[NG];
    __shared__ float  lO[NG];

    int lane = threadIdx.x;
    int tgx = blockIdx.x % TILES_X;
    int tgy = blockIdx.x / TILES_X;
    float x0 = (float)(tgx*TILE) + 0.5f, x1 = x0 + (float)(TILE-1);
    float y0 = (float)(tgy*TILE) + 0.5f, y1 = y0 + (float)(TILE-1);

    int cnt = 0;
    #pragma unroll
    for (int c = 0; c < NG; c += 64) {
        int j = c + lane;
        float4 A = SA[j];
        float4 C = SC[j];
        float rx = C.y, ry = C.z;
        bool hit = (A.x - rx <= x1) && (A.x + rx >= x0) &&
                   (A.y - ry <= y1) && (A.y + ry >= y0);
        unsigned long long m = __ballot(hit);
        int off = __popcll(m & ((1ull << lane) - 1ull));
        if (hit) {
            int idx = cnt + off;
            lA[idx] = A;
            lB[idx] = SB[j];
            lO[idx] = C.x;
        }
        cnt += (int)__popcll(m);
    }
    __syncthreads();

    float gx = (float)(tgx*TILE + (lane & (TILE-1))) + 0.5f;
    float gy = (float)(tgy*TILE + (lane / TILE)) + 0.5f;

    float T = 1.f, r = 0.f, g = 0.f, b = 0.f;
    for (int n = 0; n < cnt; ++n) {
        float4 A = lA[n];
        float4 B = lB[n];
        float  O = lO[n];
        float dx = gx - A.x;
        float dy = gy - A.y;
        float sig = 0.5f * (A.z*dx*dx + B.x*dy*dy) + A.w*dx*dy;
        float al = O * __expf(-sig);
        if (sig >= 0.f && al > (1.f/255.f)) {
            al = fminf(al, 0.999f);
            float w = al * T;
            r += w * B.y;
            g += w * B.z;
            b += w * B.w;
            T *= (1.f - al);
        }
    }

    int p = (tgy*TILE + (lane / TILE)) * IMGW + tgx*TILE + (lane & (TILE-1));
    out[p*3 + 0] = r + T * bg[0];
    out[p*3 + 1] = g + T * bg[1];
    out[p*3 + 2] = b + T * bg[2];
    out[NPIX*3 + p] = 1.f - T;
}

extern "C" void kernel_launch(void* const* d_in, const int* in_sizes, int n_in,
                              void* d_out, int out_size, void* d_ws, size_t ws_size,
                              hipStream_t stream) {
    const float* means     = (const float*)d_in[0];
    const float* scales    = (const float*)d_in[1];
    const float* quats     = (const float*)d_in[2];
    const float* opacities = (const float*)d_in[3];
    const float* sh0       = (const float*)d_in[4];
    const float* shN       = (const float*)d_in[5];
    const float* vm        = (const float*)d_in[6];
    const float* Kc        = (const float*)d_in[7];
    const float* bg        = (const float*)d_in[8];
    const int*   degp      = (const int*)  d_in[11];

    float* ws = (float*)d_ws;
    float*  tz = ws;                          // NG
    float4* UA = (float4*)(ws + NG);          // NG float4
    float4* UB = (float4*)(ws + 5*NG);
    float4* UC = (float4*)(ws + 9*NG);
    float4* SA = (float4*)(ws + 13*NG);
    float4* SB = (float4*)(ws + 17*NG);
    float4* SC = (float4*)(ws + 21*NG);

    float* out = (float*)d_out;

    preprocess_k<<<(NG + 255)/256, 256, 0, stream>>>(means, scales, quats, opacities,
                                                     sh0, shN, vm, Kc, degp,
                                                     tz, UA, UB, UC);
    sort_k<<<NG, 64, 0, stream>>>(tz, UA, UB, UC, SA, SB, SC);
    render_k<<<NTILES, 64, 0, stream>>>(SA, SB, SC, bg, out);
}